// Round 4
// baseline (372.803 us; speedup 1.0000x reference)
//
#include <hip/hip_runtime.h>

#define B_ROWS   16384
#define D_DIM    2048
#define L_LAYERS 6
#define THREADS  512                 // 8 waves/block
#define BLOCKS   512                 // exactly 2 blocks/CU (LDS-limited), uniform
#define WPB      (THREADS / 64)
#define ROWS_PER_WAVE 4              // 512*8 waves * 4 rows = 16384

// Exact algebra: x_l = c_l*x0 + u_l, u_l = sum_{i<l} b_i,
//   c_{l+1} = c_l*(1 + x0.W_l) + u_l.W_l.
// Whole net = 6 dots/row + scalar recurrence + out = c*x0 + U.
//
// R3 post-mortem: one-shot wave pipeline -> latency-bound (2.4 TB/s, VALU 13%).
// R4: 4-row loop per wave with rolling prefetch — next row's 8 float4 HBM
// loads (~900cyc) overlap current row's LDS dots + shuffle reduce + store
// (~1000cyc). Waves desync after iter 1. Still zero barriers in row phase.
__global__ __launch_bounds__(THREADS) void cross_net_kernel(
    const float* __restrict__ x,
    const float* __restrict__ W,
    const float* __restrict__ b,
    float* __restrict__ out)
{
    __shared__ float Wl[L_LAYERS][D_DIM];   // 48 KB
    __shared__ float Ul[D_DIM];             // 8 KB
    __shared__ float red[WPB][L_LAYERS];

    const int t    = threadIdx.x;
    const int lane = t & 63;
    const int wid  = t >> 6;

    // ---- setup: stage W, U = sum b_i, e[l] = (sum_{i<l} b_i).W_l ----
    {
        const int base = t * 4;             // 512 threads x 4 = 2048
        float4 prefix = make_float4(0.f, 0.f, 0.f, 0.f);
        float e_red[L_LAYERS];
        #pragma unroll
        for (int l = 0; l < L_LAYERS; ++l) {
            const float4 wv = *(const float4*)(W + l * D_DIM + base);
            const float4 bv = *(const float4*)(b + l * D_DIM + base);
            e_red[l] = prefix.x * wv.x + prefix.y * wv.y +
                       prefix.z * wv.z + prefix.w * wv.w;   // prefix BEFORE b_l
            prefix.x += bv.x; prefix.y += bv.y; prefix.z += bv.z; prefix.w += bv.w;
            *(float4*)&Wl[l][base] = wv;
        }
        *(float4*)&Ul[base] = prefix;
        #pragma unroll
        for (int l = 0; l < L_LAYERS; ++l) {
            float v = e_red[l];
            #pragma unroll
            for (int off = 32; off >= 1; off >>= 1) v += __shfl_xor(v, off, 64);
            if (lane == 0) red[wid][l] = v;
        }
    }
    __syncthreads();                        // the ONLY barrier

    float e[L_LAYERS];
    #pragma unroll
    for (int l = 0; l < L_LAYERS; ++l) {
        float s = 0.f;
        #pragma unroll
        for (int w = 0; w < WPB; ++w) s += red[w][l];
        e[l] = s;
    }

    // ---- row phase: barrier-free, one wave x 4 rows, rolling prefetch ----
    const int gw   = blockIdx.x * WPB + wid;          // 0..4095
    const int row0 = gw * ROWS_PER_WAVE;
    const float* xr  = x   + (size_t)row0 * D_DIM;
    float*       orw = out + (size_t)row0 * D_DIM;
    const int eoff = lane * 4;                        // + j*256, j=0..7

    float4 cur[8], nxt[8];
    #pragma unroll
    for (int j = 0; j < 8; ++j) cur[j] = *(const float4*)(xr + j * 256 + eoff);

    #pragma unroll
    for (int r = 0; r < ROWS_PER_WAVE; ++r) {
        // prefetch next row FIRST — stays in flight through the whole body
        if (r < ROWS_PER_WAVE - 1) {
            const float* xn = xr + D_DIM;
            #pragma unroll
            for (int j = 0; j < 8; ++j) nxt[j] = *(const float4*)(xn + j * 256 + eoff);
        }

        // 6 partial dots from LDS-resident W
        float p[L_LAYERS];
        #pragma unroll
        for (int l = 0; l < L_LAYERS; ++l) {
            float a = 0.f;
            #pragma unroll
            for (int j = 0; j < 8; ++j) {
                const float4 wv = *(const float4*)&Wl[l][j * 256 + eoff];
                a += cur[j].x * wv.x + cur[j].y * wv.y +
                     cur[j].z * wv.z + cur[j].w * wv.w;
            }
            p[l] = a;
        }

        // in-wave butterfly reduce — 6 independent chains
        #pragma unroll
        for (int off = 32; off >= 1; off >>= 1) {
            #pragma unroll
            for (int l = 0; l < L_LAYERS; ++l) p[l] += __shfl_xor(p[l], off, 64);
        }

        float c = 1.f;
        #pragma unroll
        for (int l = 0; l < L_LAYERS; ++l) c = c * (1.f + p[l]) + e[l];

        // out = c * x0 + U
        #pragma unroll
        for (int j = 0; j < 8; ++j) {
            const float4 uv = *(const float4*)&Ul[j * 256 + eoff];
            float4 o;
            o.x = c * cur[j].x + uv.x; o.y = c * cur[j].y + uv.y;
            o.z = c * cur[j].z + uv.z; o.w = c * cur[j].w + uv.w;
            *(float4*)(orw + j * 256 + eoff) = o;
        }

        xr  += D_DIM;
        orw += D_DIM;
        if (r < ROWS_PER_WAVE - 1) {
            #pragma unroll
            for (int j = 0; j < 8; ++j) cur[j] = nxt[j];  // renamed away by unroll
        }
    }
}

extern "C" void kernel_launch(void* const* d_in, const int* in_sizes, int n_in,
                              void* d_out, int out_size, void* d_ws, size_t ws_size,
                              hipStream_t stream) {
    (void)in_sizes; (void)n_in; (void)d_ws; (void)ws_size; (void)out_size;
    const float* x = (const float*)d_in[0];
    const float* W = (const float*)d_in[1];
    const float* b = (const float*)d_in[2];
    float* out = (float*)d_out;
    cross_net_kernel<<<dim3(BLOCKS), dim3(THREADS), 0, stream>>>(x, W, b, out);
}